// Round 6
// baseline (32.166 us; speedup 1.0000x reference)
//
#include <hip/hip_runtime.h>
#include <cfloat>

#define HH 800
#define WW 1024
#define NLOC 17064
#define BB 16
#define GG 48
#define NCLS 80
#define INF_A 100000000.0f

// Output section bases (in floats). Rows R = BB*NLOC = 273024.
#define LAB_BASE 0
#define REG_BASE 273024
#define TIND_BASE 1365120
#define ISIN_BASE 1638144

// #{i in [0,n): lo < i*s + hs < hi}, s = 1/inv a power of two, hs = s/2.
// Exact vs the brute-force fp32 comparisons (strict > / < of exact grid coords).
__device__ __forceinline__ int axis_count(float lo, float hi, float hs,
                                          float inv, int n) {
    int i0 = (int)floorf((lo - hs) * inv) + 1;
    i0 = max(i0, 0);
    int i1 = (int)ceilf((hi - hs) * inv) - 1;
    i1 = min(i1, n - 1);
    return max(0, i1 - i0 + 1);
}

__global__ __launch_bounds__(256)
void assign_kernel(const float* __restrict__ loc,
                   const float* __restrict__ boxes,
                   const int* __restrict__ cls,
                   const float* __restrict__ masks,
                   float* __restrict__ out) {
    const int b = blockIdx.y;
    const int tid = threadIdx.x;
    const int blockstart = blockIdx.x * 256;
    const int j0 = blockstart + tid;

    __shared__ ulonglong2 sdat[256];   // {final is_in mask, row}
    __shared__ unsigned int scm[2];    // per-image cnt>1 bitmask

    // Block-uniform pointer -> scalar (s_load) path for box reads in g-loop.
    const float4* __restrict__ bbx = reinterpret_cast<const float4*>(boxes) + b * GG;

    // Per-wave: lane g holds area[g] (g<48). One coalesced load + 3 VALU per
    // wave; consumed below via v_readlane (compile-time lane) into SGPRs.
    const int lane = tid & 63;
    const float4 bxl = bbx[min(lane, GG - 1)];
    const float areav = (bxl.z - bxl.x) * (bxl.w - bxl.y);  // exact, matches ref

    // --- closed-form per-box location count, wave 0 only (exact) ---
    if (tid < 64) {
        bool many = false;
        if (tid < GG) {
            int total = 0;
            const int wl[5] = {128, 64, 32, 16, 8};
            const int hl[5] = {100, 50, 25, 13, 7};
#pragma unroll
            for (int l = 0; l < 5; ++l) {
                const float s = (float)(8 << l);
                const float hs = 0.5f * s;
                const float inv = 1.0f / s;
                total += axis_count(bxl.x, bxl.z, hs, inv, wl[l]) *
                         axis_count(bxl.y, bxl.w, hs, inv, hl[l]);
            }
            many = total > 1;
        }
        const unsigned long long m = __ballot(many);
        if (tid == 0) { scm[0] = (unsigned int)m; scm[1] = (unsigned int)(m >> 32); }
    }
    __syncthreads();
    // Broadcast mask into SGPRs: g-loop bit tests become free SALU ops.
    const unsigned int clo = __builtin_amdgcn_readfirstlane(scm[0]);
    const unsigned int chi = __builtin_amdgcn_readfirstlane(scm[1]);
    const unsigned long long cmask = ((unsigned long long)chi << 32) | clo;

    unsigned long long finmask = 0ull;
    int row = 0;
    if (j0 < NLOC) {
        int begv, nl, sv; float lov, hiv;
        if (j0 < 12800)      { begv = 0;     nl = 12800; sv = 8;   lov = -1.0f;  hiv = 64.0f; }
        else if (j0 < 16000) { begv = 12800; nl = 3200;  sv = 16;  lov = 64.0f;  hiv = 128.0f; }
        else if (j0 < 16800) { begv = 16000; nl = 800;   sv = 32;  lov = 128.0f; hiv = 256.0f; }
        else if (j0 < 17008) { begv = 16800; nl = 208;   sv = 64;  lov = 256.0f; hiv = 512.0f; }
        else                 { begv = 17008; nl = 56;    sv = 128; lov = 512.0f; hiv = INF_A; }

        const float2 p = reinterpret_cast<const float2*>(loc)[j0];
        int xi = (int)p.x; xi = min(max(xi, 0), WW - 1);
        int yi = (int)p.y; yi = min(max(yi, 0), HH - 1);
        const float mloc = masks[(size_t)b * (HH * WW) + (size_t)yi * WW + xi];
        const bool mpos = mloc > 0.0f;

        float best = FLT_MAX;
        int bi = 0;
        // Descending g, FULLY unrolled: readlane with immediate lane index
        // pulls area[g] into an SGPR (1 instr vs ~5 VALU recompute).
        // Shift-in mask build; `<=` keeps first-occurrence argmin tie-break.
#pragma unroll
        for (int g = GG - 1; g >= 0; --g) {
            const float4 bx = bbx[g];                          // uniform -> s_load
            const bool manyg = ((cmask >> g) & 1ull) != 0ull;  // SALU bit test
            const float area = __int_as_float(
                __builtin_amdgcn_readlane(__float_as_int(areav), g));
            const float l  = p.x - bx.x;
            const float t  = p.y - bx.y;
            const float r  = bx.z - p.x;
            const float bt = bx.w - p.y;
            const float mn = fminf(fminf(l, t), fminf(r, bt));
            const float mx = fmaxf(fmaxf(l, t), fmaxf(r, bt));
            const bool in = (mn > 0.0f) && (mpos || !manyg);
            const bool sel = in && (mx >= lov) && (mx <= hiv);
            const float la = sel ? area : INF_A;
            if (la <= best) { best = la; bi = g; }
            finmask = (finmask << 1) | (in ? 1ull : 0ull);
        }

        const float4 cb = bbx[bi];  // divergent gather of winning box (L1-hot)
        int label = (best >= INF_A || !mpos) ? NCLS : cls[b * GG + bi];

        row = BB * begv + b * nl + (j0 - begv);

        out[LAB_BASE + row] = (float)label;

        const float inv_s = 1.0f / (float)sv;  // exact pow2 reciprocal
        float4 rg;
        rg.x = (p.x - cb.x) * inv_s;
        rg.y = (p.y - cb.y) * inv_s;
        rg.z = (cb.z - p.x) * inv_s;
        rg.w = (cb.w - p.y) * inv_s;
        reinterpret_cast<float4*>(out + REG_BASE)[row] = rg;

        out[TIND_BASE + row] = (float)((bi + b * GG) * (mpos ? 1 : 0));

        if (label != 0) finmask = 0ull;
    }
    sdat[tid].x = finmask;
    sdat[tid].y = (unsigned long long)row;
    __syncthreads();

    // Coalesced float4 writes of the (nrows x 48) is_in section.
    const int nrows = min(256, NLOC - blockstart);
    const int n4 = nrows * 12;  // 12 float4 per row
    float4* __restrict__ outi = reinterpret_cast<float4*>(out + ISIN_BASE);
    for (int i4 = tid; i4 < n4; i4 += 256) {
        const int lr = i4 / 12;          // magic-mul division
        const int q = i4 - lr * 12;
        const ulonglong2 d = sdat[lr];   // one ds_read_b128 per 4 outputs
        const unsigned int bits = (unsigned int)(d.x >> (q * 4)) & 15u;
        float4 v;
        v.x = (bits & 1u) ? 1.0f : 0.0f;
        v.y = (bits & 2u) ? 1.0f : 0.0f;
        v.z = (bits & 4u) ? 1.0f : 0.0f;
        v.w = (bits & 8u) ? 1.0f : 0.0f;
        outi[(int)d.y * 12 + q] = v;
    }
}

extern "C" void kernel_launch(void* const* d_in, const int* in_sizes, int n_in,
                              void* d_out, int out_size, void* d_ws, size_t ws_size,
                              hipStream_t stream) {
    const float* loc   = (const float*)d_in[0];
    const float* boxes = (const float*)d_in[1];
    const int*   cls   = (const int*)d_in[2];
    const float* masks = (const float*)d_in[3];
    float* out = (float*)d_out;

    dim3 grid((NLOC + 255) / 256, BB);
    assign_kernel<<<grid, 256, 0, stream>>>(loc, boxes, cls, masks, out);
}

// Round 7
// 24.613 us; speedup vs baseline: 1.3069x; 1.3069x over previous
//
#include <hip/hip_runtime.h>
#include <cfloat>

#define HH 800
#define WW 1024
#define NLOC 17064
#define BB 16
#define GG 48
#define NCLS 80
#define INF_A 100000000.0f

// Output section bases (in floats). Rows R = BB*NLOC = 273024.
#define LAB_BASE 0
#define REG_BASE 273024
#define TIND_BASE 1365120
#define ISIN_BASE 1638144

// #{i in [0,n): lo < i*s + hs < hi}, s = 1/inv a power of two, hs = s/2.
// Exact vs the brute-force fp32 comparisons (see analysis): strict ix > t
// <=> ix >= floor(t)+1 for ANY real t; strict ix < u <=> ix <= ceil(u)-1.
__device__ __forceinline__ int axis_count(float lo, float hi, float hs,
                                          float inv, int n) {
    int i0 = (int)floorf((lo - hs) * inv) + 1;
    i0 = max(i0, 0);
    int i1 = (int)ceilf((hi - hs) * inv) - 1;
    i1 = min(i1, n - 1);
    return max(0, i1 - i0 + 1);
}

__global__ __launch_bounds__(256)
void assign_kernel(const float* __restrict__ loc,
                   const float* __restrict__ boxes,
                   const int* __restrict__ cls,
                   const float* __restrict__ masks,
                   float* __restrict__ out) {
    const int b = blockIdx.y;
    const int tid = threadIdx.x;
    const int blockstart = blockIdx.x * 256;
    const int j0 = blockstart + tid;

    __shared__ ulonglong2 sdat[256];   // {final is_in mask, row}
    __shared__ unsigned int scm[2];    // per-image cnt>1 bitmask

    // Block-uniform pointer -> scalar (s_load) path for box reads in g-loop.
    const float4* __restrict__ bbx = reinterpret_cast<const float4*>(boxes) + b * GG;

    // --- closed-form per-box location count, wave 0 only (exact, see above) ---
    if (tid < 64) {
        bool many = false;
        if (tid < GG) {
            const float4 bx = bbx[tid];
            int total = 0;
            const int wl[5] = {128, 64, 32, 16, 8};
            const int hl[5] = {100, 50, 25, 13, 7};
#pragma unroll
            for (int l = 0; l < 5; ++l) {
                const float s = (float)(8 << l);
                const float hs = 0.5f * s;
                const float inv = 1.0f / s;
                total += axis_count(bx.x, bx.z, hs, inv, wl[l]) *
                         axis_count(bx.y, bx.w, hs, inv, hl[l]);
            }
            many = total > 1;
        }
        const unsigned long long m = __ballot(many);
        if (tid == 0) { scm[0] = (unsigned int)m; scm[1] = (unsigned int)(m >> 32); }
    }
    __syncthreads();
    // Broadcast mask into SGPRs: g-loop bit tests become free SALU ops.
    const unsigned int clo = __builtin_amdgcn_readfirstlane(scm[0]);
    const unsigned int chi = __builtin_amdgcn_readfirstlane(scm[1]);
    const unsigned long long cmask = ((unsigned long long)chi << 32) | clo;

    unsigned long long finmask = 0ull;
    int row = 0;
    if (j0 < NLOC) {
        int begv, nl, sv; float lov, hiv;
        if (j0 < 12800)      { begv = 0;     nl = 12800; sv = 8;   lov = -1.0f;  hiv = 64.0f; }
        else if (j0 < 16000) { begv = 12800; nl = 3200;  sv = 16;  lov = 64.0f;  hiv = 128.0f; }
        else if (j0 < 16800) { begv = 16000; nl = 800;   sv = 32;  lov = 128.0f; hiv = 256.0f; }
        else if (j0 < 17008) { begv = 16800; nl = 208;   sv = 64;  lov = 256.0f; hiv = 512.0f; }
        else                 { begv = 17008; nl = 56;    sv = 128; lov = 512.0f; hiv = INF_A; }

        const float2 p = reinterpret_cast<const float2*>(loc)[j0];
        int xi = (int)p.x; xi = min(max(xi, 0), WW - 1);
        int yi = (int)p.y; yi = min(max(yi, 0), HH - 1);
        const float mloc = masks[(size_t)b * (HH * WW) + (size_t)yi * WW + xi];
        const bool mpos = mloc > 0.0f;

        float best = FLT_MAX;
        int bi = 0;
        // Descending g: shift-in mask build (constant shifts); `<=` keeps
        // first-occurrence (smallest g) argmin tie-break, values exact.
#pragma unroll 8
        for (int g = GG - 1; g >= 0; --g) {
            const float4 bx = bbx[g];                         // uniform -> s_load
            const bool manyg = ((cmask >> g) & 1ull) != 0ull; // SALU bit test
            const float l  = p.x - bx.x;
            const float t  = p.y - bx.y;
            const float r  = bx.z - p.x;
            const float bt = bx.w - p.y;
            const float mn = fminf(fminf(l, t), fminf(r, bt));
            const float mx = fmaxf(fmaxf(l, t), fmaxf(r, bt));
            const bool in = (mn > 0.0f) && (mpos || !manyg);
            const bool sel = in && (mx >= lov) && (mx <= hiv);
            const float area = (bx.z - bx.x) * (bx.w - bx.y);  // exact, matches ref
            const float la = sel ? area : INF_A;
            if (la <= best) { best = la; bi = g; }
            finmask = (finmask << 1) | (in ? 1ull : 0ull);
        }

        const float4 cb = bbx[bi];  // divergent gather of winning box (L1-hot)
        int label = (best >= INF_A || !mpos) ? NCLS : cls[b * GG + bi];

        row = BB * begv + b * nl + (j0 - begv);

        out[LAB_BASE + row] = (float)label;

        const float inv_s = 1.0f / (float)sv;  // exact pow2 reciprocal
        float4 rg;
        rg.x = (p.x - cb.x) * inv_s;
        rg.y = (p.y - cb.y) * inv_s;
        rg.z = (cb.z - p.x) * inv_s;
        rg.w = (cb.w - p.y) * inv_s;
        reinterpret_cast<float4*>(out + REG_BASE)[row] = rg;

        out[TIND_BASE + row] = (float)((bi + b * GG) * (mpos ? 1 : 0));

        if (label != 0) finmask = 0ull;
    }
    sdat[tid].x = finmask;
    sdat[tid].y = (unsigned long long)row;
    __syncthreads();

    // Coalesced float4 writes of the (nrows x 48) is_in section.
    const int nrows = min(256, NLOC - blockstart);
    const int n4 = nrows * 12;  // 12 float4 per row
    float4* __restrict__ outi = reinterpret_cast<float4*>(out + ISIN_BASE);
    for (int i4 = tid; i4 < n4; i4 += 256) {
        const int lr = i4 / 12;          // magic-mul division
        const int q = i4 - lr * 12;
        const ulonglong2 d = sdat[lr];   // one ds_read_b128 per 4 outputs
        const unsigned int bits = (unsigned int)(d.x >> (q * 4)) & 15u;
        float4 v;
        v.x = (bits & 1u) ? 1.0f : 0.0f;
        v.y = (bits & 2u) ? 1.0f : 0.0f;
        v.z = (bits & 4u) ? 1.0f : 0.0f;
        v.w = (bits & 8u) ? 1.0f : 0.0f;
        outi[(int)d.y * 12 + q] = v;
    }
}

extern "C" void kernel_launch(void* const* d_in, const int* in_sizes, int n_in,
                              void* d_out, int out_size, void* d_ws, size_t ws_size,
                              hipStream_t stream) {
    const float* loc   = (const float*)d_in[0];
    const float* boxes = (const float*)d_in[1];
    const int*   cls   = (const int*)d_in[2];
    const float* masks = (const float*)d_in[3];
    float* out = (float*)d_out;

    dim3 grid((NLOC + 255) / 256, BB);
    assign_kernel<<<grid, 256, 0, stream>>>(loc, boxes, cls, masks, out);
}